// Round 1
// baseline (162.033 us; speedup 1.0000x reference)
//
#include <hip/hip_runtime.h>
#include <math.h>

#define IMG  1024
#define TS   32          // output tile
#define HALO 3
#define XT   38          // TS + 2*HALO
#define S1T  36
#define S2T  34

__device__ __forceinline__ float sigf(float y) {
    return 1.0f / (1.0f + __expf(-y));
}

// 9-tap accumulate for 4 vertically-stacked outputs sharing a 6x3 input patch
__device__ __forceinline__ void acc9(float acc[4], const float v[6][3], const float* w9) {
#pragma unroll
    for (int dy = 0; dy < 3; ++dy)
#pragma unroll
        for (int dx = 0; dx < 3; ++dx) {
            float ww = w9[dy * 3 + dx];
#pragma unroll
            for (int rr = 0; rr < 4; ++rr)
                acc[rr] += ww * v[rr + dy][dx];
        }
}

// Collapse (lw1,lb1,lw2,lb2) into a single 6->2 affine map: ws[0..11]=Wc[2][6], ws[12..13]=bc[2]
__global__ void combine_lin(const float* __restrict__ lw1, const float* __restrict__ lb1,
                            const float* __restrict__ lw2, const float* __restrict__ lb2,
                            float* __restrict__ ws) {
    int t = threadIdx.x;
    if (t < 12) {
        int o = t / 6, c = t % 6;
        float acc = 0.0f;
        for (int k = 0; k < 128; ++k) acc += lw2[o * 128 + k] * lw1[k * 6 + c];
        ws[o * 6 + c] = acc;
    } else if (t < 14) {
        int o = t - 12;
        float acc = lb2[o];
        for (int k = 0; k < 128; ++k) acc += lw2[o * 128 + k] * lb1[k];
        ws[12 + o] = acc;
    }
}

__global__ __launch_bounds__(256, 2)
void unet_fused(const float* __restrict__ x, const float* __restrict__ x2,
                const float* __restrict__ w1a, const float* __restrict__ b1a,
                const float* __restrict__ w2a, const float* __restrict__ b2a,
                const float* __restrict__ w3a, const float* __restrict__ b3a,
                const float* __restrict__ w1b, const float* __restrict__ b1b,
                const float* __restrict__ w2b, const float* __restrict__ b2b,
                const float* __restrict__ w3b, const float* __restrict__ b3b,
                const float* __restrict__ wsc,
                float* __restrict__ out)
{
    __shared__ float xt[2][3][XT * XT];   // input halos, both branches
    __shared__ float s1[2][S1T * S1T];    // conv1+sigmoid (global rows -2..+33 of tile)
    __shared__ float s2[2][S2T * S2T];    // conv2+sigmoid (-1..+32)
    __shared__ float s3[2][TS * TS];      // conv3+sigmoid (interior)

    const int tid = threadIdx.x;
    const int bx = blockIdx.x, by = blockIdx.y;
    const int row0 = by * TS - HALO, col0 = bx * TS - HALO;

    const float* W1[2] = {w1a, w1b};
    const float* W2[2] = {w2a, w2b};
    const float* W3[2] = {w3a, w3b};
    const float* B1[2] = {b1a, b1b};
    const float* B2[2] = {b2a, b2b};
    const float* B3[2] = {b3a, b3b};

    // ---------------- halo load (both inputs) ----------------
    for (int idx = tid; idx < 3 * XT * XT; idx += 256) {
        int pl = idx / (XT * XT);
        int i  = idx - pl * (XT * XT);
        int r = i / XT, c = i - r * XT;
        int gr = row0 + r, gc = col0 + c;
        bool ok = ((unsigned)gr < (unsigned)IMG) && ((unsigned)gc < (unsigned)IMG);
        float v0 = 0.0f, v1 = 0.0f;
        if (ok) {
            long g = (long)pl * (IMG * IMG) + (long)gr * IMG + gc;
            v0 = x[g];
            v1 = x2[g];
        }
        xt[0][pl][i] = v0;
        xt[1][pl][i] = v1;
    }
    __syncthreads();

    // ---------------- stage 1: 3x3 conv (3ch) + sigmoid over 36x36 ----------------
    for (int br = 0; br < 2; ++br) {
        float w[27];
#pragma unroll
        for (int i = 0; i < 27; ++i) w[i] = W1[br][i];
        const float bias = B1[br][0];
        for (int item = tid; item < S1T * 9; item += 256) {
            int c = item % S1T, rg = item / S1T;
            int r0 = rg * 4;
            float acc[4] = {bias, bias, bias, bias};
#pragma unroll
            for (int ic = 0; ic < 3; ++ic) {
                const float* xp = &xt[br][ic][r0 * XT + c];
                float v[6][3];
#pragma unroll
                for (int rr = 0; rr < 6; ++rr)
#pragma unroll
                    for (int cc = 0; cc < 3; ++cc)
                        v[rr][cc] = xp[rr * XT + cc];
                acc9(acc, v, &w[ic * 9]);
            }
            // store, zeroing out-of-image positions (zero padding for later convs)
            int gc1 = col0 + 1 + c;
            bool cok = (unsigned)gc1 < (unsigned)IMG;
            float* so = &s1[br][r0 * S1T + c];
#pragma unroll
            for (int rr = 0; rr < 4; ++rr) {
                int gr1 = row0 + 1 + r0 + rr;
                bool ok = cok && ((unsigned)gr1 < (unsigned)IMG);
                so[rr * S1T] = ok ? sigf(acc[rr]) : 0.0f;
            }
        }
    }
    __syncthreads();

    // ---------------- stage 2: 3x3 conv (4ch: x0..x2, s1) + sigmoid over 34x34 ----------------
    for (int br = 0; br < 2; ++br) {
        float w[36];
#pragma unroll
        for (int i = 0; i < 36; ++i) w[i] = W2[br][i];
        const float bias = B2[br][0];
        for (int item = tid; item < S2T * 9; item += 256) {
            int c = item % S2T, rg = item / S2T;
            int r0 = rg * 4;
            float acc[4] = {bias, bias, bias, bias};
#pragma unroll
            for (int ic = 0; ic < 3; ++ic) {
                float v[6][3];
#pragma unroll
                for (int rr = 0; rr < 6; ++rr) {
                    int rrow = r0 + 1 + rr; if (rrow > XT - 1) rrow = XT - 1;  // clamp (tail rows unused)
#pragma unroll
                    for (int cc = 0; cc < 3; ++cc)
                        v[rr][cc] = xt[br][ic][rrow * XT + (c + 1 + cc)];
                }
                acc9(acc, v, &w[ic * 9]);
            }
            {
                float v[6][3];
#pragma unroll
                for (int rr = 0; rr < 6; ++rr) {
                    int rrow = r0 + rr; if (rrow > S1T - 1) rrow = S1T - 1;    // clamp (tail rows unused)
#pragma unroll
                    for (int cc = 0; cc < 3; ++cc)
                        v[rr][cc] = s1[br][rrow * S1T + (c + cc)];
                }
                acc9(acc, v, &w[27]);
            }
            int gc2 = col0 + 2 + c;
            bool cok = (unsigned)gc2 < (unsigned)IMG;
            float* so = &s2[br][r0 * S2T + c];
#pragma unroll
            for (int rr = 0; rr < 4; ++rr) {
                int srow = r0 + rr;
                if (srow < S2T) {
                    int gr2 = row0 + 2 + srow;
                    bool ok = cok && ((unsigned)gr2 < (unsigned)IMG);
                    so[rr * S2T] = ok ? sigf(acc[rr]) : 0.0f;
                }
            }
        }
    }
    __syncthreads();

    // ---------------- stage 3: 3x3 conv (5ch) + sigmoid over 32x32 (interior only) ----------------
    for (int br = 0; br < 2; ++br) {
        float w[45];
#pragma unroll
        for (int i = 0; i < 45; ++i) w[i] = W3[br][i];
        const float bias = B3[br][0];
        {
            int item = tid;                  // exactly 32 cols x 8 strips = 256 items
            int c = item & 31, rg = item >> 5;
            int r0 = rg * 4;
            float acc[4] = {bias, bias, bias, bias};
#pragma unroll
            for (int ic = 0; ic < 3; ++ic) {
                float v[6][3];
#pragma unroll
                for (int rr = 0; rr < 6; ++rr)
#pragma unroll
                    for (int cc = 0; cc < 3; ++cc)
                        v[rr][cc] = xt[br][ic][(r0 + 2 + rr) * XT + (c + 2 + cc)];
                acc9(acc, v, &w[ic * 9]);
            }
            {
                float v[6][3];
#pragma unroll
                for (int rr = 0; rr < 6; ++rr)
#pragma unroll
                    for (int cc = 0; cc < 3; ++cc)
                        v[rr][cc] = s1[br][(r0 + 1 + rr) * S1T + (c + 1 + cc)];
                acc9(acc, v, &w[27]);
            }
            {
                float v[6][3];
#pragma unroll
                for (int rr = 0; rr < 6; ++rr)
#pragma unroll
                    for (int cc = 0; cc < 3; ++cc)
                        v[rr][cc] = s2[br][(r0 + rr) * S2T + (c + cc)];
                acc9(acc, v, &w[36]);
            }
            float* so = &s3[br][r0 * TS + c];
#pragma unroll
            for (int rr = 0; rr < 4; ++rr)
                so[rr * TS] = sigf(acc[rr]);   // interior pixels: always inside image
        }
    }
    __syncthreads();

    // ---------------- outputs: den_x1, den_x2 (HWC), outfeature = Wc*(a-b)+bc ----------------
    float wcr[14];
#pragma unroll
    for (int i = 0; i < 14; ++i) wcr[i] = wsc[i];
    const long out1 = (long)2 * IMG * IMG;          // den_x1 offset
    const long out2 = out1 + (long)6 * IMG * IMG;   // den_x2 offset
    for (int p = tid; p < TS * TS; p += 256) {
        int r = p >> 5, c = p & 31;
        long gr = (long)by * TS + r, gc = (long)bx * TS + c;
        long pix = gr * IMG + gc;
        float a[6], b[6];
#pragma unroll
        for (int ch = 0; ch < 3; ++ch) {
            a[ch] = xt[0][ch][(r + 3) * XT + (c + 3)];
            b[ch] = xt[1][ch][(r + 3) * XT + (c + 3)];
        }
        a[3] = s1[0][(r + 2) * S1T + (c + 2)];
        b[3] = s1[1][(r + 2) * S1T + (c + 2)];
        a[4] = s2[0][(r + 1) * S2T + (c + 1)];
        b[4] = s2[1][(r + 1) * S2T + (c + 1)];
        a[5] = s3[0][r * TS + c];
        b[5] = s3[1][r * TS + c];

        float* p1 = out + out1 + pix * 6;
        float* p2 = out + out2 + pix * 6;
#pragma unroll
        for (int ch = 0; ch < 6; ++ch) { p1[ch] = a[ch]; p2[ch] = b[ch]; }

        float o0 = wcr[12], o1 = wcr[13];
#pragma unroll
        for (int ch = 0; ch < 6; ++ch) {
            float d = a[ch] - b[ch];
            o0 += wcr[ch]     * d;
            o1 += wcr[6 + ch] * d;
        }
        out[pix * 2]     = o0;
        out[pix * 2 + 1] = o1;
    }
}

extern "C" void kernel_launch(void* const* d_in, const int* in_sizes, int n_in,
                              void* d_out, int out_size, void* d_ws, size_t ws_size,
                              hipStream_t stream) {
    const float* x   = (const float*)d_in[0];
    const float* x2  = (const float*)d_in[1];
    const float* w1a = (const float*)d_in[2];
    const float* b1a = (const float*)d_in[3];
    const float* w2a = (const float*)d_in[4];
    const float* b2a = (const float*)d_in[5];
    const float* w3a = (const float*)d_in[6];
    const float* b3a = (const float*)d_in[7];
    const float* w1b = (const float*)d_in[8];
    const float* b1b = (const float*)d_in[9];
    const float* w2b = (const float*)d_in[10];
    const float* b2b = (const float*)d_in[11];
    const float* w3b = (const float*)d_in[12];
    const float* b3b = (const float*)d_in[13];
    const float* lw1 = (const float*)d_in[14];
    const float* lb1 = (const float*)d_in[15];
    const float* lw2 = (const float*)d_in[16];
    const float* lb2 = (const float*)d_in[17];
    float* ws  = (float*)d_ws;
    float* out = (float*)d_out;

    combine_lin<<<1, 64, 0, stream>>>(lw1, lb1, lw2, lb2, ws);

    dim3 grid(IMG / TS, IMG / TS);   // 32 x 32 blocks
    unet_fused<<<grid, 256, 0, stream>>>(x, x2,
                                         w1a, b1a, w2a, b2a, w3a, b3a,
                                         w1b, b1b, w2b, b2b, w3b, b3b,
                                         ws, out);
}

// Round 2
// 155.712 us; speedup vs baseline: 1.0406x; 1.0406x over previous
//
#include <hip/hip_runtime.h>
#include <math.h>

#define IMG  1024
#define TS   32          // output tile
#define HALO 3
#define XT   38          // TS + 2*HALO
#define S1T  36
#define S2T  34

__device__ __forceinline__ float sigf(float y) {
    return 1.0f / (1.0f + __expf(-y));
}

// 9-tap accumulate for 4 vertically-stacked outputs sharing a 6x3 input patch
__device__ __forceinline__ void acc9(float acc[4], const float v[6][3], const float* w9) {
#pragma unroll
    for (int dy = 0; dy < 3; ++dy)
#pragma unroll
        for (int dx = 0; dx < 3; ++dx) {
            float ww = w9[dy * 3 + dx];
#pragma unroll
            for (int rr = 0; rr < 4; ++rr)
                acc[rr] += ww * v[rr + dy][dx];
        }
}

__global__ __launch_bounds__(256, 4)
void unet_fused(const float* __restrict__ x, const float* __restrict__ x2,
                const float* __restrict__ w1a, const float* __restrict__ b1a,
                const float* __restrict__ w2a, const float* __restrict__ b2a,
                const float* __restrict__ w3a, const float* __restrict__ b3a,
                const float* __restrict__ w1b, const float* __restrict__ b1b,
                const float* __restrict__ w2b, const float* __restrict__ b2b,
                const float* __restrict__ w3b, const float* __restrict__ b3b,
                const float* __restrict__ lw1, const float* __restrict__ lb1,
                const float* __restrict__ lw2, const float* __restrict__ lb2,
                float* __restrict__ out)
{
    // single-branch LDS footprint: 17328 + 5184 + 4624 + 64 = ~27.2 KB  -> 4+ blocks/CU
    __shared__ float xt[3][XT * XT];   // input halo, current branch
    __shared__ float s1[S1T * S1T];    // conv1+sigmoid (global rows -2..+33 of tile)
    __shared__ float s2[S2T * S2T];    // conv2+sigmoid (-1..+32)
    __shared__ float wc[14];           // collapsed 6->2 affine: Wc[2][6], bc[2]

    const int tid = threadIdx.x;
    const int bx = blockIdx.x, by = blockIdx.y;
    const int row0 = by * TS - HALO, col0 = bx * TS - HALO;

    // this thread's fixed output mapping: col c, rows r0..r0+3 of the 32x32 tile
    const int c_out = tid & 31;
    const int r0_out = (tid >> 5) * 4;

    // ---- collapsed linear map (redundant per block; ~1792 FMA on 14 lanes, hidden) ----
    if (tid < 12) {
        int o = tid / 6, ch = tid % 6;
        float acc = 0.0f;
        for (int k = 0; k < 128; ++k) acc += lw2[o * 128 + k] * lw1[k * 6 + ch];
        wc[tid] = acc;
    } else if (tid < 14) {
        int o = tid - 12;
        float acc = lb2[o];
        for (int k = 0; k < 128; ++k) acc += lw2[o * 128 + k] * lb1[k];
        wc[tid] = acc;
    }

    const float* XS[2] = {x, x2};
    const float* W1[2] = {w1a, w1b};
    const float* W2[2] = {w2a, w2b};
    const float* W3[2] = {w3a, w3b};
    const float* B1[2] = {b1a, b1b};
    const float* B2[2] = {b2a, b2b};
    const float* B3[2] = {b3a, b3b};

    const long out1 = (long)2 * IMG * IMG;          // den_x1 offset
    const long out2 = out1 + (long)6 * IMG * IMG;   // den_x2 offset

    float areg[4][6];    // branch-a outputs for this thread's 4 pixels

#pragma unroll
    for (int br = 0; br < 2; ++br) {
        // ---------------- halo load ----------------
        const float* xin = XS[br];
        for (int idx = tid; idx < 3 * XT * XT; idx += 256) {
            int pl = idx / (XT * XT);
            int i  = idx - pl * (XT * XT);
            int r = i / XT, cc = i - r * XT;
            int gr = row0 + r, gc = col0 + cc;
            bool ok = ((unsigned)gr < (unsigned)IMG) && ((unsigned)gc < (unsigned)IMG);
            float v = 0.0f;
            if (ok) v = xin[(long)pl * (IMG * IMG) + (long)gr * IMG + gc];
            xt[pl][i] = v;
        }
        __syncthreads();

        // ---------------- stage 1: 3x3 conv (3ch) + sigmoid over 36x36 ----------------
        {
            float w[27];
#pragma unroll
            for (int i = 0; i < 27; ++i) w[i] = W1[br][i];
            const float bias = B1[br][0];
            for (int item = tid; item < S1T * 9; item += 256) {
                int c = item % S1T, rg = item / S1T;
                int r0 = rg * 4;
                float acc[4] = {bias, bias, bias, bias};
#pragma unroll
                for (int ic = 0; ic < 3; ++ic) {
                    const float* xp = &xt[ic][r0 * XT + c];
                    float v[6][3];
#pragma unroll
                    for (int rr = 0; rr < 6; ++rr)
#pragma unroll
                        for (int cc = 0; cc < 3; ++cc)
                            v[rr][cc] = xp[rr * XT + cc];
                    acc9(acc, v, &w[ic * 9]);
                }
                int gc1 = col0 + 1 + c;
                bool cok = (unsigned)gc1 < (unsigned)IMG;
                float* so = &s1[r0 * S1T + c];
#pragma unroll
                for (int rr = 0; rr < 4; ++rr) {
                    int gr1 = row0 + 1 + r0 + rr;
                    bool ok = cok && ((unsigned)gr1 < (unsigned)IMG);
                    so[rr * S1T] = ok ? sigf(acc[rr]) : 0.0f;
                }
            }
        }
        __syncthreads();

        // ---------------- stage 2: 3x3 conv (4ch) + sigmoid over 34x34 ----------------
        {
            float w[36];
#pragma unroll
            for (int i = 0; i < 36; ++i) w[i] = W2[br][i];
            const float bias = B2[br][0];
            for (int item = tid; item < S2T * 9; item += 256) {
                int c = item % S2T, rg = item / S2T;
                int r0 = rg * 4;
                float acc[4] = {bias, bias, bias, bias};
#pragma unroll
                for (int ic = 0; ic < 3; ++ic) {
                    float v[6][3];
#pragma unroll
                    for (int rr = 0; rr < 6; ++rr) {
                        int rrow = r0 + 1 + rr; if (rrow > XT - 1) rrow = XT - 1;  // tail rows unused
#pragma unroll
                        for (int cc = 0; cc < 3; ++cc)
                            v[rr][cc] = xt[ic][rrow * XT + (c + 1 + cc)];
                    }
                    acc9(acc, v, &w[ic * 9]);
                }
                {
                    float v[6][3];
#pragma unroll
                    for (int rr = 0; rr < 6; ++rr) {
                        int rrow = r0 + rr; if (rrow > S1T - 1) rrow = S1T - 1;    // tail rows unused
#pragma unroll
                        for (int cc = 0; cc < 3; ++cc)
                            v[rr][cc] = s1[rrow * S1T + (c + cc)];
                    }
                    acc9(acc, v, &w[27]);
                }
                int gc2 = col0 + 2 + c;
                bool cok = (unsigned)gc2 < (unsigned)IMG;
                float* so = &s2[r0 * S2T + c];
#pragma unroll
                for (int rr = 0; rr < 4; ++rr) {
                    int srow = r0 + rr;
                    if (srow < S2T) {
                        int gr2 = row0 + 2 + srow;
                        bool ok = cok && ((unsigned)gr2 < (unsigned)IMG);
                        so[rr * S2T] = ok ? sigf(acc[rr]) : 0.0f;
                    }
                }
            }
        }
        __syncthreads();

        // ---------------- stage 3 (registers) + gather + write ----------------
        {
            float w[45];
#pragma unroll
            for (int i = 0; i < 45; ++i) w[i] = W3[br][i];
            const float bias = B3[br][0];
            const int c = c_out, r0 = r0_out;
            float acc[4] = {bias, bias, bias, bias};
#pragma unroll
            for (int ic = 0; ic < 3; ++ic) {
                float v[6][3];
#pragma unroll
                for (int rr = 0; rr < 6; ++rr)
#pragma unroll
                    for (int cc = 0; cc < 3; ++cc)
                        v[rr][cc] = xt[ic][(r0 + 2 + rr) * XT + (c + 2 + cc)];
                acc9(acc, v, &w[ic * 9]);
            }
            {
                float v[6][3];
#pragma unroll
                for (int rr = 0; rr < 6; ++rr)
#pragma unroll
                    for (int cc = 0; cc < 3; ++cc)
                        v[rr][cc] = s1[(r0 + 1 + rr) * S1T + (c + 1 + cc)];
                acc9(acc, v, &w[27]);
            }
            {
                float v[6][3];
#pragma unroll
                for (int rr = 0; rr < 6; ++rr)
#pragma unroll
                    for (int cc = 0; cc < 3; ++cc)
                        v[rr][cc] = s2[(r0 + rr) * S2T + (c + cc)];
                acc9(acc, v, &w[36]);
            }

            // gather this thread's 4 pixels x 6 channels
            float cur[4][6];
#pragma unroll
            for (int rr = 0; rr < 4; ++rr) {
#pragma unroll
                for (int ch = 0; ch < 3; ++ch)
                    cur[rr][ch] = xt[ch][(r0 + 3 + rr) * XT + (c + 3)];
                cur[rr][3] = s1[(r0 + 2 + rr) * S1T + (c + 2)];
                cur[rr][4] = s2[(r0 + 1 + rr) * S2T + (c + 1)];
                cur[rr][5] = sigf(acc[rr]);
            }

            // write den_x1 / den_x2 in HWC
            const long denOff = (br == 0) ? out1 : out2;
#pragma unroll
            for (int rr = 0; rr < 4; ++rr) {
                long gr = (long)by * TS + r0 + rr;
                long pix = gr * IMG + ((long)bx * TS + c);
                float* pd = out + denOff + pix * 6;
#pragma unroll
                for (int ch = 0; ch < 6; ++ch) pd[ch] = cur[rr][ch];
            }

            if (br == 0) {
#pragma unroll
                for (int rr = 0; rr < 4; ++rr)
#pragma unroll
                    for (int ch = 0; ch < 6; ++ch) areg[rr][ch] = cur[rr][ch];
            } else {
                float wcr[14];
#pragma unroll
                for (int i = 0; i < 14; ++i) wcr[i] = wc[i];
#pragma unroll
                for (int rr = 0; rr < 4; ++rr) {
                    float o0 = wcr[12], o1 = wcr[13];
#pragma unroll
                    for (int ch = 0; ch < 6; ++ch) {
                        float d = areg[rr][ch] - cur[rr][ch];
                        o0 += wcr[ch]     * d;
                        o1 += wcr[6 + ch] * d;
                    }
                    long gr = (long)by * TS + r0 + rr;
                    long pix = gr * IMG + ((long)bx * TS + c);
                    out[pix * 2]     = o0;
                    out[pix * 2 + 1] = o1;
                }
            }
        }
        __syncthreads();   // LDS reuse barrier before branch 1 halo load
    }
}

extern "C" void kernel_launch(void* const* d_in, const int* in_sizes, int n_in,
                              void* d_out, int out_size, void* d_ws, size_t ws_size,
                              hipStream_t stream) {
    const float* x   = (const float*)d_in[0];
    const float* x2  = (const float*)d_in[1];
    const float* w1a = (const float*)d_in[2];
    const float* b1a = (const float*)d_in[3];
    const float* w2a = (const float*)d_in[4];
    const float* b2a = (const float*)d_in[5];
    const float* w3a = (const float*)d_in[6];
    const float* b3a = (const float*)d_in[7];
    const float* w1b = (const float*)d_in[8];
    const float* b1b = (const float*)d_in[9];
    const float* w2b = (const float*)d_in[10];
    const float* b2b = (const float*)d_in[11];
    const float* w3b = (const float*)d_in[12];
    const float* b3b = (const float*)d_in[13];
    const float* lw1 = (const float*)d_in[14];
    const float* lb1 = (const float*)d_in[15];
    const float* lw2 = (const float*)d_in[16];
    const float* lb2 = (const float*)d_in[17];
    float* out = (float*)d_out;

    dim3 grid(IMG / TS, IMG / TS);   // 32 x 32 blocks
    unet_fused<<<grid, 256, 0, stream>>>(x, x2,
                                         w1a, b1a, w2a, b2a, w3a, b3a,
                                         w1b, b1b, w2b, b2b, w3b, b3b,
                                         lw1, lb1, lw2, lb2, out);
}